// Round 7
// baseline (238.756 us; speedup 1.0000x reference)
//
#include <hip/hip_runtime.h>
#include <math.h>

#define N_TOTAL 40960
#define M_EV    4096
#define KNN     32
#define FEAT    192   // CIN + 2*PDIM

typedef float v2f __attribute__((ext_vector_type(2)));

__device__ __forceinline__ float dot4f(float4 a, float4 b) {
    return fmaf(a.w, b.w, fmaf(a.z, b.z, fmaf(a.y, b.y, a.x * b.x)));
}

// monotone float->uint key: a<b  <=>  fkey(a)<fkey(b)
__device__ __forceinline__ unsigned fkey(float f) {
    unsigned b = __float_as_uint(f);
    return b ^ ((unsigned)((int)b >> 31) | 0x80000000u);
}

// count of set bits in m at positions below this lane (64-bit mbcnt idiom)
__device__ __forceinline__ int mbcnt64(unsigned long long m) {
    return __builtin_amdgcn_mbcnt_hi((unsigned)(m >> 32),
           __builtin_amdgcn_mbcnt_lo((unsigned)m, 0u));
}

// ---------------------------------------------------------------------------
// Kernel 1: space = x@W_space + b_space  [N,4];  prop = x@W_prop + b_prop [N,64]
// ---------------------------------------------------------------------------
__global__ __launch_bounds__(256) void k_linear(
    const float* __restrict__ x,
    const float* __restrict__ Wp, const float* __restrict__ bp,
    const float* __restrict__ Ws, const float* __restrict__ bs,
    float* __restrict__ prop, float* __restrict__ space)
{
    __shared__ float xs[16 * 64];
    const int t = threadIdx.x;
    const int rowbase = blockIdx.x * 16;

    {
        float4 v = *(const float4*)(x + rowbase * 64 + t * 4);
        *(float4*)(xs + t * 4) = v;
    }
    __syncthreads();

    const int j  = t & 63;
    const int rg = t >> 6;
    float a0 = 0.f, a1 = 0.f, a2 = 0.f, a3 = 0.f;
#pragma unroll 8
    for (int c = 0; c < 64; ++c) {
        float w = Wp[c * 64 + j];
        a0 = fmaf(xs[(rg * 4 + 0) * 64 + c], w, a0);
        a1 = fmaf(xs[(rg * 4 + 1) * 64 + c], w, a1);
        a2 = fmaf(xs[(rg * 4 + 2) * 64 + c], w, a2);
        a3 = fmaf(xs[(rg * 4 + 3) * 64 + c], w, a3);
    }
    const float bj = bp[j];
    prop[(rowbase + rg * 4 + 0) * 64 + j] = a0 + bj;
    prop[(rowbase + rg * 4 + 1) * 64 + j] = a1 + bj;
    prop[(rowbase + rg * 4 + 2) * 64 + j] = a2 + bj;
    prop[(rowbase + rg * 4 + 3) * 64 + j] = a3 + bj;

    if (t < 64) {
        const int r = t >> 2, s = t & 3;
        float a = 0.f;
#pragma unroll 8
        for (int c = 0; c < 64; ++c)
            a = fmaf(xs[r * 64 + c], Ws[c * 4 + s], a);
        space[(rowbase + r) * 4 + s] = a + bs[s];
    }
}

// ---------------------------------------------------------------------------
// Kernel 2: exact kNN, threshold-compact + ballot radix-select.
//  Round 16: SoA LDS + packed dual-FP32 chains (fixing round-11's failure
//  at the root).
//   * Round-11 regressed because v2f operands were marshalled out of AoS
//     b128 loads (mov-heavy, VGPR +20). Here tiles are staged into LDS as
//     FIVE scalar arrays (s_x/s_y/s_z/s_w/s_h): a lane reads 2 adjacent
//     candidates' components as natural float2 (ds_read_b64, one addr reg
//     + immediate offsets, 2-way bank = free) -> v_pk_fma_f32 operands are
//     born as aligned VGPR pairs, ZERO marshalling.
//   * Per 2 candidates per query: 4 pk_fma + 2 min = 6 VALU vs 10 scalar
//     (-40% on the pole pipe for distance; pass-2 compare/compact similar).
//   * QPW 8->4 (QPB=16, grid 2560): splatted -q pairs cost 32 VGPRs, not
//     64. Per-query chain VALU is QPW-independent; the doubled per-query
//     LDS reads land on the ~20%-utilized LDS pipe.
//   * Numerics: packed fma == per-element fma, same x,y,z,w order, same
//     staged 0.5f*dot4f(c,c) -> pass1/pass2/select chains bitwise
//     consistent; exact-compaction invariant preserved. Compaction order
//     changes (even/odd halves) but selection uses index VALUES and the
//     final op is order-invariant (mean/max).
//   * Fallback risk bounded: if LLVM scalarizes v2f, cost degenerates to
//     the scalar version (operands already pairs; no marshalling).
//   Revert from round 15: pass 2 is LDS-staged again (de-staging measured
//   86.0->86.6-87.4).
// ---------------------------------------------------------------------------
#define QPW   4
#define QPB   16
#define TILEC 1024
#define CCAP  128

__global__ __launch_bounds__(256, 4) void k_knn(
    const float4* __restrict__ space4,
    int* __restrict__ knn_idx, float* __restrict__ knn_w,
    int* __restrict__ bad)
{
    __shared__ float  s_x[TILEC];         // 4096 B
    __shared__ float  s_y[TILEC];         // 4096 B
    __shared__ float  s_z[TILEC];         // 4096 B
    __shared__ float  s_w[TILEC];         // 4096 B
    __shared__ float  s_h[TILEC];         // 4096 B (0.5*|c|^2)
    __shared__ ushort s_ci[QPB * CCAP];   // 4096 B  => 24576 B

    const int t = threadIdx.x;
    const int w = t >> 6;                 // wave 0..3
    const int l = t & 63;
    const int qb = blockIdx.x * QPB;
    const int ebase = (qb / M_EV) * M_EV;

    float4 qcs[QPW];                      // plain q (select path + sqq)
    v2f nqx[QPW], nqy[QPW], nqz[QPW], nqw[QPW];  // splatted -q components
#pragma unroll
    for (int s = 0; s < QPW; ++s) {
        float4 q = space4[qb + w * QPW + s];
        qcs[s] = q;
        nqx[s] = (v2f){-q.x, -q.x};
        nqy[s] = (v2f){-q.y, -q.y};
        nqz[s] = (v2f){-q.z, -q.z};
        nqw[s] = (v2f){-q.w, -q.w};
    }

    v2f mn2[QPW];
#pragma unroll
    for (int s = 0; s < QPW; ++s) mn2[s] = (v2f){INFINITY, INFINITY};

    // ---- pass 1: per-lane slice minima of dh (SoA LDS, 2 cands/iter) ----
#pragma unroll 1
    for (int tile = 0; tile < M_EV / TILEC; ++tile) {
        __syncthreads();
#pragma unroll
        for (int u = 0; u < TILEC / 256; ++u) {
            int ci = u * 256 + t;
            float4 c = space4[ebase + tile * TILEC + ci];
            s_x[ci] = c.x; s_y[ci] = c.y; s_z[ci] = c.z; s_w[ci] = c.w;
            s_h[ci] = 0.5f * dot4f(c, c);
        }
        __syncthreads();
#pragma unroll 2
        for (int j = 0; j < TILEC / 128; ++j) {
            int ci2 = j * 128 + 2 * l;
            v2f cx2 = *(const v2f*)(s_x + ci2);
            v2f cy2 = *(const v2f*)(s_y + ci2);
            v2f cz2 = *(const v2f*)(s_z + ci2);
            v2f cw2 = *(const v2f*)(s_w + ci2);
            v2f hc2 = *(const v2f*)(s_h + ci2);
#pragma unroll
            for (int s = 0; s < QPW; ++s) {
                v2f dh = __builtin_elementwise_fma(nqx[s], cx2, hc2);
                dh = __builtin_elementwise_fma(nqy[s], cy2, dh);
                dh = __builtin_elementwise_fma(nqz[s], cz2, dh);
                dh = __builtin_elementwise_fma(nqw[s], cw2, dh);
                mn2[s].x = fminf(mn2[s].x, dh.x);
                mn2[s].y = fminf(mn2[s].y, dh.y);
            }
        }
    }

    // ---- T[s] = 32nd smallest of the 64 lane minima (bitonic, 4q/stage) ----
    float v[QPW];
#pragma unroll
    for (int s = 0; s < QPW; ++s) v[s] = fminf(mn2[s].x, mn2[s].y);
#pragma unroll
    for (int k = 2; k <= 64; k <<= 1) {
#pragma unroll
        for (int j = k >> 1; j >= 1; j >>= 1) {
            bool tmn = (((l & k) == 0) == ((l & j) == 0));
#pragma unroll
            for (int s = 0; s < QPW; ++s) {
                float p = __shfl_xor(v[s], j, 64);
                v[s] = tmn ? fminf(v[s], p) : fmaxf(v[s], p);
            }
        }
    }
    float T[QPW];
#pragma unroll
    for (int s = 0; s < QPW; ++s) T[s] = __shfl(v[s], 31, 64);

    // ---- pass 2: ballot-compact with dh<=T (identical packed chain) ----
    int cw[QPW];
#pragma unroll
    for (int s = 0; s < QPW; ++s) cw[s] = 0;

#pragma unroll 1
    for (int tile = 0; tile < M_EV / TILEC; ++tile) {
        __syncthreads();
#pragma unroll
        for (int u = 0; u < TILEC / 256; ++u) {
            int ci = u * 256 + t;
            float4 c = space4[ebase + tile * TILEC + ci];
            s_x[ci] = c.x; s_y[ci] = c.y; s_z[ci] = c.z; s_w[ci] = c.w;
            s_h[ci] = 0.5f * dot4f(c, c);
        }
        __syncthreads();
#pragma unroll 2
        for (int j = 0; j < TILEC / 128; ++j) {
            int ci2 = j * 128 + 2 * l;
            v2f cx2 = *(const v2f*)(s_x + ci2);
            v2f cy2 = *(const v2f*)(s_y + ci2);
            v2f cz2 = *(const v2f*)(s_z + ci2);
            v2f cw2 = *(const v2f*)(s_w + ci2);
            v2f hc2 = *(const v2f*)(s_h + ci2);
#pragma unroll
            for (int s = 0; s < QPW; ++s) {
                v2f dh = __builtin_elementwise_fma(nqx[s], cx2, hc2);
                dh = __builtin_elementwise_fma(nqy[s], cy2, dh);
                dh = __builtin_elementwise_fma(nqz[s], cz2, dh);
                dh = __builtin_elementwise_fma(nqw[s], cw2, dh);
                bool pe = (dh.x <= T[s]);
                bool po = (dh.y <= T[s]);
                unsigned long long me = __ballot(pe);
                unsigned long long mo = __ballot(po);
                int base = cw[s];
                if (pe) {
                    int pos = base + mbcnt64(me);
                    if (pos < CCAP)
                        s_ci[(w * QPW + s) * CCAP + pos] =
                            (ushort)(tile * TILEC + ci2);
                }
                if (po) {
                    int pos = base + (int)__popcll(me) + mbcnt64(mo);
                    if (pos < CCAP)
                        s_ci[(w * QPW + s) * CCAP + pos] =
                            (ushort)(tile * TILEC + ci2 + 1);
                }
                cw[s] = base + (int)__popcll(me) + (int)__popcll(mo);
            }
        }
    }
    // own wave wrote its own compact region; DS ops in-order per wave.

    // ---- exact select per query: ballot radix-select ----
#pragma unroll
    for (int s = 0; s < QPW; ++s) {
        const int qi = w * QPW + s;
        const int q  = qb + qi;
        const int cnt = cw[s];                     // wave-uniform
        if (l == 0) bad[q] = (cnt > CCAP) ? 1 : 0;
        if (cnt <= CCAP) {
            const float4 qc = qcs[s];
            const float sqq = dot4f(qc, qc);

            // entry A (slots 0..63)
            const int vA = (l < cnt);
            int iA = vA ? (int)s_ci[qi * CCAP + l] : 0;
            float dA;
            {
                float4 c = space4[ebase + iA];
                float hc = 0.5f * dot4f(c, c);
                float dh = fmaf(-qc.x, c.x, hc);
                dh = fmaf(-qc.y, c.y, dh);
                dh = fmaf(-qc.z, c.z, dh);
                dh = fmaf(-qc.w, c.w, dh);
                dA = dh;
            }
            unsigned uA = vA ? fkey(dA) : 0xFFFFFFFFu;

            unsigned long long sA, sB;
            float dB = 0.f; int iB = 0;

            if (cnt <= 64) {
                // ---- fast path: A only ----
                unsigned kth = 0u;
#pragma unroll
                for (int b = 31; b >= 0; --b) {
                    unsigned cand = kth | (1u << b);
                    int c = __popcll(__ballot(uA < cand));
                    if (c < KNN) kth = cand;
                }
                unsigned long long ltA = __ballot(uA < kth);
                int take = KNN - __popcll(ltA);    // >= 1
                unsigned long long eqA = __ballot(uA == kth);
                if (__popcll(eqA) == take) {
                    sA = ltA | eqA;
                } else {
                    int ki = 0;
#pragma unroll 1
                    for (int b = 12; b >= 0; --b) {
                        int cand = ki | (1 << b);
                        int c = __popcll(__ballot(iA < cand) & eqA);
                        if (c < take) ki = cand;
                    }
                    sA = ltA | (__ballot(iA <= ki) & eqA);
                }
                sB = 0ull;
            } else {
                // ---- full path: A + B ----
                const int vB = (64 + l < cnt);
                iB = vB ? (int)s_ci[qi * CCAP + 64 + l] : 0;
                {
                    float4 c = space4[ebase + iB];
                    float hc = 0.5f * dot4f(c, c);
                    float dh = fmaf(-qc.x, c.x, hc);
                    dh = fmaf(-qc.y, c.y, dh);
                    dh = fmaf(-qc.z, c.z, dh);
                    dh = fmaf(-qc.w, c.w, dh);
                    dB = dh;
                }
                unsigned uB = vB ? fkey(dB) : 0xFFFFFFFFu;

                unsigned kth = 0u;
#pragma unroll
                for (int b = 31; b >= 0; --b) {
                    unsigned cand = kth | (1u << b);
                    int c = __popcll(__ballot(uA < cand))
                          + __popcll(__ballot(uB < cand));
                    if (c < KNN) kth = cand;
                }
                unsigned long long ltA = __ballot(uA < kth);
                unsigned long long ltB = __ballot(uB < kth);
                int take = KNN - (__popcll(ltA) + __popcll(ltB)); // >= 1
                unsigned long long eqA = __ballot(uA == kth);
                unsigned long long eqB = __ballot(uB == kth);
                if (__popcll(eqA) + __popcll(eqB) == take) {
                    sA = ltA | eqA; sB = ltB | eqB;
                } else {
                    int ki = 0;
#pragma unroll 1
                    for (int b = 12; b >= 0; --b) {
                        int cand = ki | (1 << b);
                        int c = __popcll(__ballot(iA < cand) & eqA)
                              + __popcll(__ballot(iB < cand) & eqB);
                        if (c < take) ki = cand;
                    }
                    sA = ltA | (__ballot(iA <= ki) & eqA);
                    sB = ltB | (__ballot(iB <= ki) & eqB);
                }
            }

            // scatter-write: popc(sA)+popc(sB) == 32 exactly
            if ((sA >> l) & 1ull) {
                int pos = mbcnt64(sA);
                float dt = fmaxf(fmaf(2.0f, dA, sqq), 0.0f); // d^2 = 2dh + |q|^2
                knn_idx[q * KNN + pos] = ebase + iA;
                knn_w[q * KNN + pos]   = __expf(-10.0f * dt);
            }
            if ((sB >> l) & 1ull) {
                int pos = __popcll(sA) + mbcnt64(sB);
                float dt = fmaxf(fmaf(2.0f, dB, sqq), 0.0f);
                knn_idx[q * KNN + pos] = ebase + iB;
                knn_w[q * KNN + pos]   = __expf(-10.0f * dt);
            }
        }
    }
}

// ---------------------------------------------------------------------------
// Kernel 2b: exact fallback for flagged queries (expected never to fire).
// ---------------------------------------------------------------------------
__global__ __launch_bounds__(256) void k_fix(
    const float4* __restrict__ space4, const int* __restrict__ bad,
    int* __restrict__ knn_idx, float* __restrict__ knn_w)
{
    const int q = blockIdx.x * 256 + threadIdx.x;
    if (!bad[q]) return;
    const int eb = (q / M_EV) * M_EV;
    float4 qc = space4[q];
    float sqq = dot4f(qc, qc);
    float ld[KNN]; int li[KNN];
    for (int e = 0; e < KNN; ++e) { ld[e] = INFINITY; li[e] = 0; }
    float cm = INFINITY; int mp = 0;
    for (int c = 0; c < M_EV; ++c) {
        float4 cc = space4[eb + c];
        float d = fmaf(-2.0f, dot4f(qc, cc), sqq + dot4f(cc, cc));
        if (d < cm) {
            ld[mp] = d; li[mp] = c;
            cm = ld[0]; mp = 0;
            for (int e = 1; e < KNN; ++e) if (ld[e] > cm) { cm = ld[e]; mp = e; }
        }
    }
    for (int e = 0; e < KNN; ++e) {
        knn_idx[q * KNN + e] = eb + li[e];
        knn_w[q * KNN + e]   = __expf(-10.0f * fmaxf(ld[e], 0.0f));
    }
}

// ---------------------------------------------------------------------------
// Kernel 3 (fused agg+out). REVERTED to round-5 form (16-row, FSTR 18):
// the round-6 32-row re-block regressed total by ~10us (doubled barriers).
// ---------------------------------------------------------------------------
#define FSTR 18

__global__ __launch_bounds__(256) void k_tail(
    const float* __restrict__ x, const float* __restrict__ prop,
    const int* __restrict__ knn_idx, const float* __restrict__ knn_w,
    const float* __restrict__ Wo, const float* __restrict__ bo,
    float* __restrict__ out)
{
    __shared__ float fs2[FEAT * FSTR];   // 13824 B
    __shared__ float s_w[48 * 128];      // 24576 B

    const int t = threadIdx.x;
    const int qb = blockIdx.x * 16;

    {
        const int r = t >> 4, c4 = (t & 15) * 4;
        float4 v = *(const float4*)(x + (size_t)(qb + r) * 64 + c4);
        fs2[(c4 + 0) * FSTR + r] = v.x;
        fs2[(c4 + 1) * FSTR + r] = v.y;
        fs2[(c4 + 2) * FSTR + r] = v.z;
        fs2[(c4 + 3) * FSTR + r] = v.w;
    }

    {
        const int p = t & 63;
#pragma unroll 1
        for (int s = 0; s < 4; ++s) {
            const int r = __builtin_amdgcn_readfirstlane(s * 4 + (t >> 6));
            const int q = qb + r;
            float acc = 0.f, mx = -INFINITY;
#pragma unroll 8
            for (int e = 0; e < KNN; ++e) {
                int   ix = knn_idx[q * KNN + e];
                float wv = knn_w[q * KNN + e];
                float g  = wv * prop[(size_t)ix * 64 + p];
                acc += g;
                mx = fmaxf(mx, g);
            }
            fs2[(64 + p) * FSTR + r]  = acc * (1.0f / 32.0f);
            fs2[(128 + p) * FSTR + r] = mx;
        }
    }

    const int rg = t >> 5;
    const int c4 = (t & 31) * 4;
    float acc0[4] = {0.f, 0.f, 0.f, 0.f};
    float acc1[4] = {0.f, 0.f, 0.f, 0.f};

#pragma unroll 1
    for (int cc = 0; cc < 4; ++cc) {
        __syncthreads();
#pragma unroll
        for (int u = 0; u < 6; ++u) {
            int fi = u * 1024 + t * 4;
            *(float4*)(s_w + fi) = *(const float4*)(Wo + (size_t)cc * 48 * 128 + fi);
        }
        __syncthreads();
#pragma unroll 4
        for (int ii = 0; ii < 48; ++ii) {
            int i = cc * 48 + ii;
            float2 f = *(const float2*)(fs2 + i * FSTR + rg * 2);
            float4 wv = *(const float4*)(s_w + ii * 128 + c4);
            acc0[0] = fmaf(f.x, wv.x, acc0[0]); acc0[1] = fmaf(f.x, wv.y, acc0[1]);
            acc0[2] = fmaf(f.x, wv.z, acc0[2]); acc0[3] = fmaf(f.x, wv.w, acc0[3]);
            acc1[0] = fmaf(f.y, wv.x, acc1[0]); acc1[1] = fmaf(f.y, wv.y, acc1[1]);
            acc1[2] = fmaf(f.y, wv.z, acc1[2]); acc1[3] = fmaf(f.y, wv.w, acc1[3]);
        }
    }

    const float4 bc = *(const float4*)(bo + c4);
    float4 o0, o1;
    o0.x = fmaxf(acc0[0] + bc.x, 0.f); o0.y = fmaxf(acc0[1] + bc.y, 0.f);
    o0.z = fmaxf(acc0[2] + bc.z, 0.f); o0.w = fmaxf(acc0[3] + bc.w, 0.f);
    o1.x = fmaxf(acc1[0] + bc.x, 0.f); o1.y = fmaxf(acc1[1] + bc.y, 0.f);
    o1.z = fmaxf(acc1[2] + bc.z, 0.f); o1.w = fmaxf(acc1[3] + bc.w, 0.f);
    *(float4*)(out + (size_t)(qb + rg * 2 + 0) * 128 + c4) = o0;
    *(float4*)(out + (size_t)(qb + rg * 2 + 1) * 128 + c4) = o1;
}

// ---------------------------------------------------------------------------
extern "C" void kernel_launch(void* const* d_in, const int* in_sizes, int n_in,
                              void* d_out, int out_size, void* d_ws, size_t ws_size,
                              hipStream_t stream) {
    const float* x  = (const float*)d_in[0];
    const float* Ws = (const float*)d_in[2];
    const float* bs = (const float*)d_in[3];
    const float* Wp = (const float*)d_in[4];
    const float* bp = (const float*)d_in[5];
    const float* Wo = (const float*)d_in[6];
    const float* bo = (const float*)d_in[7];
    float* out = (float*)d_out;

    float* space = (float*)d_ws;                          // N*4
    float* prop  = space + (size_t)N_TOTAL * 4;           // N*64
    int*   kidx  = (int*)(prop + (size_t)N_TOTAL * 64);   // N*32
    float* kw    = (float*)(kidx + (size_t)N_TOTAL * KNN);// N*32
    int*   bad   = (int*)(kw + (size_t)N_TOTAL * KNN);    // N

    k_linear<<<N_TOTAL / 16, 256, 0, stream>>>(x, Wp, bp, Ws, bs, prop, space);
    k_knn   <<<N_TOTAL / QPB, 256, 0, stream>>>((const float4*)space, kidx, kw, bad);
    k_fix   <<<N_TOTAL / 256, 256, 0, stream>>>((const float4*)space, bad, kidx, kw);
    k_tail  <<<N_TOTAL / 16, 256, 0, stream>>>(x, prop, kidx, kw, Wo, bo, out);
}